// Round 2
// baseline (312.926 us; speedup 1.0000x reference)
//
#include <hip/hip_runtime.h>
#include <math.h>

// Sparsemax over rows: out = max(z - tau, 0), tau s.t. sum(max(z - tau, 0)) = 1.
// One block per row; row (4096 fp32) in registers (16/thread).
// Key insight: tau >= zmax - 1, so support subset of {z > zmax - 1} (tiny for
// Gaussian rows). Compact candidates to LDS; wave 0 computes tau EXACTLY via
// 64-lane bitonic sort + prefix sum + k-rule. Only 3 block barriers on the
// common path (vs 26 for per-iteration bisection reductions).

constexpr int S   = 4096;
constexpr int TPB = 256;
constexpr int VPT = S / TPB;   // 16 values per thread
constexpr int NW  = TPB / 64;  // 4 waves
constexpr int CAP = 512;       // LDS candidate capacity

#define NEGBIG (-1e30f)

__global__ __launch_bounds__(TPB) void sparsemax_kernel(
    const float* __restrict__ scores,
    const int*   __restrict__ mask,
    float*       __restrict__ out)
{
    const int row  = blockIdx.x;
    const int tid  = threadIdx.x;
    const int lane = tid & 63;
    const int wid  = tid >> 6;

    const float* srow = scores + (size_t)row * S;
    const int*   mrow = mask   + (size_t)row * S;
    float*       orow = out    + (size_t)row * S;

    float z[VPT];
    #pragma unroll
    for (int c = 0; c < VPT / 4; ++c) {
        const int idx = c * (TPB * 4) + tid * 4;
        const float4 s4 = *reinterpret_cast<const float4*>(srow + idx);
        const int4   m4 = *reinterpret_cast<const int4*>(mrow + idx);
        z[c * 4 + 0] = m4.x ? s4.x : NEGBIG;
        z[c * 4 + 1] = m4.y ? s4.y : NEGBIG;
        z[c * 4 + 2] = m4.z ? s4.z : NEGBIG;
        z[c * 4 + 3] = m4.w ? s4.w : NEGBIG;
    }

    __shared__ float red[NW];
    __shared__ float red2[NW];
    __shared__ float tauS;
    __shared__ int   cnt;
    __shared__ float cand[CAP];

    if (tid == 0) cnt = 0;

    // ---- row max (wave shuffle + one LDS hop) ----
    float m = z[0];
    #pragma unroll
    for (int j = 1; j < VPT; ++j) m = fmaxf(m, z[j]);
    #pragma unroll
    for (int o = 1; o < 64; o <<= 1) m = fmaxf(m, __shfl_xor(m, o, 64));
    if (lane == 0) red[wid] = m;
    __syncthreads();                                  // barrier 1 (also cnt=0)
    const float zmax = fmaxf(fmaxf(red[0], red[1]), fmaxf(red[2], red[3]));
    const float t0 = zmax - 1.0f;

    // ---- compact candidates (z > zmax-1) into LDS ----
    float lv[VPT];
    int ln = 0;
    #pragma unroll
    for (int j = 0; j < VPT; ++j) {
        if (z[j] > t0) lv[ln++] = z[j];
    }
    if (ln) {
        int base = atomicAdd(&cnt, ln);
        for (int i = 0; i < ln; ++i)
            if (base + i < CAP) cand[base + i] = lv[i];
    }
    __syncthreads();                                  // barrier 2
    const int n = cnt;

    if (n <= 64) {
        // ---- exact tau: wave 0 bitonic sort (descending) + cumsum + k-rule ----
        if (wid == 0) {
            float v = (lane < n) ? cand[lane] : NEGBIG;
            #pragma unroll
            for (int k = 2; k <= 64; k <<= 1) {
                #pragma unroll
                for (int j = k >> 1; j > 0; j >>= 1) {
                    const float pv = __shfl_xor(v, j, 64);
                    const bool lower   = (lane & j) == 0;
                    const bool dir_asc = (lane & k) != 0;   // inverted net -> descending
                    const float mn = fminf(v, pv), mx = fmaxf(v, pv);
                    v = (lower == dir_asc) ? mn : mx;
                }
            }
            float cs = v;
            #pragma unroll
            for (int o = 1; o < 64; o <<= 1) {
                const float t = __shfl_up(cs, o, 64);
                if (lane >= o) cs += t;
            }
            const bool sup = (lane < n) && (1.0f + (float)(lane + 1) * v > cs);
            const unsigned long long bal = __ballot(sup);
            const int ks = __popcll(bal);               // support size (prefix)
            const float csk = __shfl(cs, ks - 1, 64);
            if (lane == 0) tauS = (csk - 1.0f) / (float)ks;
        }
        __syncthreads();                              // barrier 3
    } else if (n <= CAP) {
        // ---- rare: wave 0 bisection + refinement over LDS candidates ----
        if (wid == 0) {
            float w[CAP / 64];
            #pragma unroll
            for (int i = 0; i < CAP / 64; ++i) {
                const int id = lane + i * 64;
                w[i] = (id < n) ? cand[id] : NEGBIG;
            }
            float lo = t0, hi = zmax;
            for (int it = 0; it < 14; ++it) {
                const float mid = 0.5f * (lo + hi);
                float f = 0.0f;
                #pragma unroll
                for (int i = 0; i < CAP / 64; ++i) f += fmaxf(w[i] - mid, 0.0f);
                #pragma unroll
                for (int o = 1; o < 64; o <<= 1) f += __shfl_xor(f, o, 64);
                if (f > 1.0f) lo = mid; else hi = mid;
            }
            const float tc = 0.5f * (lo + hi);
            float s = 0.0f, kk = 0.0f;
            #pragma unroll
            for (int i = 0; i < CAP / 64; ++i)
                if (w[i] > tc) { s += w[i]; kk += 1.0f; }
            #pragma unroll
            for (int o = 1; o < 64; o <<= 1) {
                s  += __shfl_xor(s, o, 64);
                kk += __shfl_xor(kk, o, 64);
            }
            if (lane == 0) tauS = (s - 1.0f) / kk;    // kk>=1: zmax > tc always
        }
        __syncthreads();
    } else {
        // ---- ultra-rare: full-block bisection over register-resident z ----
        float lo = t0, hi = zmax;
        #pragma unroll 1
        for (int it = 0; it < 12; ++it) {
            const float mid = 0.5f * (lo + hi);
            float f = 0.0f;
            #pragma unroll
            for (int j = 0; j < VPT; ++j) f += fmaxf(z[j] - mid, 0.0f);
            #pragma unroll
            for (int o = 1; o < 64; o <<= 1) f += __shfl_xor(f, o, 64);
            __syncthreads();
            if (lane == 0) red[wid] = f;
            __syncthreads();
            f = (red[0] + red[1]) + (red[2] + red[3]);
            if (f > 1.0f) lo = mid; else hi = mid;
        }
        const float tc = 0.5f * (lo + hi);
        float s = 0.0f, kk = 0.0f;
        #pragma unroll
        for (int j = 0; j < VPT; ++j)
            if (z[j] > tc) { s += z[j]; kk += 1.0f; }
        #pragma unroll
        for (int o = 1; o < 64; o <<= 1) {
            s  += __shfl_xor(s, o, 64);
            kk += __shfl_xor(kk, o, 64);
        }
        __syncthreads();
        if (lane == 0) { red[wid] = s; red2[wid] = kk; }
        __syncthreads();
        s  = (red[0] + red[1]) + (red[2] + red[3]);
        kk = (red2[0] + red2[1]) + (red2[2] + red2[3]);
        if (tid == 0) tauS = (s - 1.0f) / kk;
        __syncthreads();
    }

    const float tau = tauS;

    // ---- write out ----
    #pragma unroll
    for (int c = 0; c < VPT / 4; ++c) {
        const int idx = c * (TPB * 4) + tid * 4;
        float4 o4;
        o4.x = fmaxf(z[c * 4 + 0] - tau, 0.0f);
        o4.y = fmaxf(z[c * 4 + 1] - tau, 0.0f);
        o4.z = fmaxf(z[c * 4 + 2] - tau, 0.0f);
        o4.w = fmaxf(z[c * 4 + 3] - tau, 0.0f);
        *reinterpret_cast<float4*>(orow + idx) = o4;
    }
}

extern "C" void kernel_launch(void* const* d_in, const int* in_sizes, int n_in,
                              void* d_out, int out_size, void* d_ws, size_t ws_size,
                              hipStream_t stream) {
    const float* scores = (const float*)d_in[0];
    const int*   mask   = (const int*)d_in[1];
    float*       out    = (float*)d_out;
    const int B = in_sizes[0] / S;  // 8192
    sparsemax_kernel<<<dim3(B), dim3(TPB), 0, stream>>>(scores, mask, out);
}